// Round 14
// baseline (417.521 us; speedup 1.0000x reference)
//
#include <hip/hip_runtime.h>

// VariationalMPS R16: R14/R15 base with eB + norm-B inner loops rebuilt for
// LDS-port efficiency: 4x4 microtile (1x ds_read_b128 As-transposed stride-36
// + 1x ds_read_b128 Bs per 16 FMAs = 2x port efficiency), 4-way k-split
// (z = t>>7, 128 thr each, 4 chunks each), 4-way LDS reduce aliasing dead
// buffers. LDS 53KB (R12's 104KB blowup avoided), R11's proven 2-barrier +
// prefetch skeleton. Port model: eB 20us -> 10us. eA (R14), norm-A, preps,
// dot, loss verbatim. Pre-registered: null here kills the port model.

#define D 128
#define W 8
#define NS 40
#define NPAIR 20
#define HALF2 10
#define MSZ (D * 2 * D)        // 32768
#define HSZ (W * W * 2 * 2)    // 256
#define M2SZ (D * 4 * D)       // 65536  [a][I][c] = a*512+I*128+c
#define H2SZ (W * W * 4 * 4)   // 1024   [w][x][I][J]
#define LSZ (D * W * D)        // 131072 [a][w][b] (= [p][x][q] after B)
#define NSZ (D * D)            // 16384
#define T2SZ (D * W * D * 4)   // 524288 row(p,x)*512 + b*4+J
#define TNSZ (4 * D * D)       // 65536  [I][p][b]

#define OFF_M2 0
#define OFF_MR2 (OFF_M2 + NPAIR * M2SZ)
#define OFF_H2 (OFF_MR2 + HALF2 * M2SZ)
#define OFF_HR2 (OFF_H2 + NPAIR * H2SZ)
#define OFF_LL (OFF_HR2 + HALF2 * H2SZ)
#define OFF_LR (OFF_LL + LSZ)
#define OFF_NL (OFF_LR + LSZ)
#define OFF_NR (OFF_NL + NSZ)
#define OFF_T2L (OFF_NR + NSZ)
#define OFF_T2R (OFF_T2L + T2SZ)
#define OFF_TNL (OFF_T2R + T2SZ)
#define OFF_TNR (OFF_TNL + TNSZ)
#define OFF_PART (OFF_TNR + TNSZ)
#define OFF_PARTN (OFF_PART + 128)

// ---------------- prep1: pair GEMMs M2 (640 blocks) + H2 (block 640) --------
__global__ __launch_bounds__(256) void k_prep1(const float* __restrict__ Min,
                                               const float* __restrict__ Hin,
                                               float* __restrict__ ws) {
    __shared__ float As[32 * 34];
    __shared__ float Bs[32 * 68];
    int bid = blockIdx.x, t = threadIdx.x;
    if (bid < 640) {
        int m = bid >> 5, tile = bid & 31;
        int r0 = (tile & 7) * 32, c0 = (tile >> 3) * 64;
        const float* A = Min + (2 * m) * MSZ;
        const float* B = Min + (2 * m + 1) * MSZ;
        float* C = ws + OFF_M2 + m * M2SZ;
        int ty = t >> 4, tx = t & 15;
        float a00 = 0, a01 = 0, a02 = 0, a03 = 0;
        float a10 = 0, a11 = 0, a12 = 0, a13 = 0;
        for (int c = 0; c < 4; ++c) {
            int k0 = c * 32;
            __syncthreads();
            {
                int rr = t >> 3, kq = t & 7;
                int row = r0 + rr;
                const float4 v = *(const float4*)&A[(row >> 1) * 256 + (row & 1) * 128 + k0 + kq * 4];
                float* dst = &As[kq * 136 + rr];
                dst[0] = v.x; dst[34] = v.y; dst[68] = v.z; dst[102] = v.w;
            }
#pragma unroll
            for (int u = 0; u < 2; ++u) {
                int e = u * 256 + t;
                int kk = e >> 4, cq = e & 15;
                const float4 v = *(const float4*)&B[(k0 + kk) * 256 + c0 + cq * 4];
                *(float4*)&Bs[kk * 68 + cq * 4] = v;
            }
            __syncthreads();
#pragma unroll 8
            for (int kk = 0; kk < 32; ++kk) {
                float2 av = *(float2*)&As[kk * 34 + 2 * ty];
                float4 bv = *(float4*)&Bs[kk * 68 + 4 * tx];
                a00 += av.x * bv.x; a01 += av.x * bv.y; a02 += av.x * bv.z; a03 += av.x * bv.w;
                a10 += av.y * bv.x; a11 += av.y * bv.y; a12 += av.y * bv.z; a13 += av.y * bv.w;
            }
        }
        int r = r0 + 2 * ty, cc = c0 + 4 * tx;
        int a = r >> 1, i2 = cc >> 7, cd = cc & 127;
        float4 v0; v0.x = a00; v0.y = a01; v0.z = a02; v0.w = a03;
        float4 v1; v1.x = a10; v1.y = a11; v1.z = a12; v1.w = a13;
        *(float4*)&C[a * 512 + (0 * 2 + i2) * 128 + cd] = v0;
        *(float4*)&C[a * 512 + (1 * 2 + i2) * 128 + cd] = v1;
    } else {
        for (int idx = t; idx < NPAIR * H2SZ; idx += 256) {
            int m = idx >> 10, r = idx & 1023;
            int w = r >> 7, x = (r >> 4) & 7, I = (r >> 2) & 3, J = r & 3;
            int i1 = I >> 1, i2 = I & 1, j1 = J >> 1, j2 = J & 1;
            const float* Ha = Hin + (2 * m) * HSZ;
            const float* Hb = Hin + (2 * m + 1) * HSZ;
            float s = 0.f;
#pragma unroll
            for (int v = 0; v < 8; ++v)
                s += Ha[w * 32 + v * 4 + i1 * 2 + j1] * Hb[v * 32 + x * 4 + i2 * 2 + j2];
            ws[OFF_H2 + idx] = s;
        }
    }
}

// ---------------- prep2: rev transposes + env init --------------------------
#define PR_MR (HALF2 * M2SZ)
#define PR_HR (PR_MR + HALF2 * H2SZ)
#define PR_TOT (PR_HR + 2 * LSZ + 2 * NSZ)
__global__ __launch_bounds__(256) void k_prep2(float* __restrict__ ws) {
    for (int idx = blockIdx.x * 256 + threadIdx.x; idx < PR_TOT; idx += gridDim.x * 256) {
        if (idx < PR_MR) {
            int kr = idx >> 16, r = idx & 65535;
            int a = r >> 9, I = (r >> 7) & 3, p = r & 127;
            ws[OFF_MR2 + idx] = ws[OFF_M2 + (19 - kr) * M2SZ + p * 512 + I * 128 + a];
        } else if (idx < PR_HR) {
            int e = idx - PR_MR;
            int kr = e >> 10, r = e & 1023;
            int w = r >> 7, x = (r >> 4) & 7, lo = r & 15;
            ws[OFF_HR2 + e] = ws[OFF_H2 + (19 - kr) * H2SZ + x * 128 + w * 16 + lo];
        } else {
            int e = idx - PR_HR;
            int off; float v = 0.f;
            if (e < LSZ)            { off = OFF_LL + e; if (e == 0) v = 1.f; }
            else if (e < 2 * LSZ)   { int r = e - LSZ; off = OFF_LR + r; if (r == (W - 1) * D) v = 1.f; }
            else if (e < 2 * LSZ + NSZ) { int r = e - 2 * LSZ; off = OFF_NL + r; if (r == 0) v = 1.f; }
            else                    { int r = e - 2 * LSZ - NSZ; off = OFF_NR + r; if (r == 0) v = 1.f; }
            ws[off] = v;
        }
    }
}

// ---------------- phase A (512 threads, grid 160) — R14 verbatim ------------
__global__ __launch_bounds__(512) void k_A2(float* __restrict__ ws, int k) {
    __shared__ __align__(16) float sm[17920];
    int bid = blockIdx.x, t = threadIdx.x;
    int z = t >> 8, tl = t & 255;
    if (bid < 128) {
        int side = bid >> 6;
        int eb = bid & 63;
        int b0 = (eb & 7) * 16;
        int p0 = (eb >> 3) * 16;
        const float* Lsrc = ws + (side ? OFF_LR : OFF_LL);
        const float* m2 = ws + (side ? OFF_MR2 : OFF_M2) + k * M2SZ;
        const float* h2 = ws + (side ? OFF_HR2 : OFF_H2) + k * H2SZ;
        float* T2 = ws + (side ? OFF_T2R : OFF_T2L);
        float* Ls = sm + z * 6400;         // [32a][16b][12w-pad] stride 200
        float* ms = sm + 12800 + z * 2048; // [32a][16p][4I]
        float* hs = sm + 16896;            // [32 wI][32 xJ]
#pragma unroll
        for (int u = 0; u < 2; ++u) {   // stage h2
            int e = u * 512 + t;
            int w = e >> 7, I = (e >> 5) & 3, x = (e >> 2) & 7, J = e & 3;
            hs[e] = h2[w * 128 + x * 16 + I * 4 + J];
        }
        int b_l = tl & 15, p_l = tl >> 4;
        float acc[8][4];
#pragma unroll
        for (int w = 0; w < 8; ++w)
#pragma unroll
            for (int I = 0; I < 4; ++I) acc[w][I] = 0.f;
        int la[4], lw[4], lb[4], maa[2], mI[2], mpq[2];
#pragma unroll
        for (int u = 0; u < 4; ++u) {
            int e = u * 256 + tl;
            la[u] = e >> 5; lw[u] = (e >> 2) & 7; lb[u] = e & 3;
        }
#pragma unroll
        for (int u = 0; u < 2; ++u) {
            int e = u * 256 + tl;
            maa[u] = e >> 4; mI[u] = (e >> 2) & 3; mpq[u] = e & 3;
        }
        float4 pl[4], pm[2];
        {
            int a0 = z * 64;
#pragma unroll
            for (int u = 0; u < 4; ++u)
                pl[u] = *(const float4*)&Lsrc[(a0 + la[u]) * 1024 + lw[u] * 128 + b0 + lb[u] * 4];
#pragma unroll
            for (int u = 0; u < 2; ++u)
                pm[u] = *(const float4*)&m2[(a0 + maa[u]) * 512 + mI[u] * 128 + p0 + mpq[u] * 4];
        }
        for (int c = 0; c < 2; ++c) {
            __syncthreads();
#pragma unroll
            for (int u = 0; u < 4; ++u) {
                float* dst = &Ls[la[u] * 200 + lb[u] * 48 + lw[u]];
                dst[0] = pl[u].x; dst[12] = pl[u].y; dst[24] = pl[u].z; dst[36] = pl[u].w;
            }
#pragma unroll
            for (int u = 0; u < 2; ++u) {   // ms[aa][p][I]: scatter over p
                int base = maa[u] * 64 + mpq[u] * 16 + mI[u];
                ms[base] = pm[u].x; ms[base + 4] = pm[u].y;
                ms[base + 8] = pm[u].z; ms[base + 12] = pm[u].w;
            }
            if (c == 0) {
                int a0 = z * 64 + 32;
#pragma unroll
                for (int u = 0; u < 4; ++u)
                    pl[u] = *(const float4*)&Lsrc[(a0 + la[u]) * 1024 + lw[u] * 128 + b0 + lb[u] * 4];
#pragma unroll
                for (int u = 0; u < 2; ++u)
                    pm[u] = *(const float4*)&m2[(a0 + maa[u]) * 512 + mI[u] * 128 + p0 + mpq[u] * 4];
            }
            __syncthreads();
#pragma unroll 4
            for (int aa = 0; aa < 32; ++aa) {
                float4 l0 = *(float4*)&Ls[aa * 200 + b_l * 12];
                float4 l1 = *(float4*)&Ls[aa * 200 + b_l * 12 + 4];
                float4 mv = *(float4*)&ms[aa * 64 + p_l * 4];
                float lv[8] = {l0.x, l0.y, l0.z, l0.w, l1.x, l1.y, l1.z, l1.w};
#pragma unroll
                for (int w = 0; w < 8; ++w) {
                    acc[w][0] += lv[w] * mv.x;
                    acc[w][1] += lv[w] * mv.y;
                    acc[w][2] += lv[w] * mv.z;
                    acc[w][3] += lv[w] * mv.w;
                }
            }
        }
        // reduce z1 -> z0 (red aliases Ls region, dead after sync)
        __syncthreads();
        float* red = sm;
        if (z == 1) {
#pragma unroll
            for (int w = 0; w < 8; ++w) {
                float4 v; v.x = acc[w][0]; v.y = acc[w][1]; v.z = acc[w][2]; v.w = acc[w][3];
                *(float4*)&red[tl * 32 + w * 4] = v;
            }
        }
        __syncthreads();
        if (z == 0) {
#pragma unroll
            for (int w = 0; w < 8; ++w) {
                float4 v = *(float4*)&red[tl * 32 + w * 4];
                acc[w][0] += v.x; acc[w][1] += v.y; acc[w][2] += v.z; acc[w][3] += v.w;
            }
            float o[32];
#pragma unroll
            for (int xJ = 0; xJ < 32; ++xJ) o[xJ] = 0.f;
#pragma unroll
            for (int wI = 0; wI < 32; ++wI) {
                float tv = acc[wI >> 2][wI & 3];
#pragma unroll
                for (int xJ = 0; xJ < 32; ++xJ) o[xJ] += tv * hs[wI * 32 + xJ];
            }
            int b = b0 + b_l, p = p0 + p_l;
#pragma unroll
            for (int x = 0; x < 8; ++x) {
                float4 v; v.x = o[x * 4]; v.y = o[x * 4 + 1];
                v.z = o[x * 4 + 2]; v.w = o[x * 4 + 3];
                *(float4*)&T2[p * 4096 + x * 512 + b * 4] = v;
            }
        }
    } else {
        int g = (bid - 128) * 2 + z;     // 0..63 (R11 norm A verbatim)
        int side = g >> 5;
        int nn = g & 31;
        int b0 = (nn & 3) * 32;
        int c0 = (nn >> 2) * 64;
        const float* Nsrc = ws + (side ? OFF_NR : OFF_NL);
        const float* m2 = ws + (side ? OFF_MR2 : OFF_M2) + k * M2SZ;
        float* Tn = ws + (side ? OFF_TNR : OFF_TNL);
        float* As = sm + z * 3264;       // [32][33]
        float* Bs = sm + z * 3264 + 1056; // [32][68]
        int ty = tl >> 4, tx = tl & 15;
        float a00 = 0, a01 = 0, a02 = 0, a03 = 0;
        float a10 = 0, a11 = 0, a12 = 0, a13 = 0;
        for (int c = 0; c < 4; ++c) {
            int a0 = c * 32;
            __syncthreads();
#pragma unroll
            for (int u = 0; u < 4; ++u) {
                int e = u * 256 + tl;
                int kk = e >> 5, col = e & 31;
                As[kk * 33 + col] = Nsrc[(a0 + kk) * 128 + b0 + col];
            }
#pragma unroll
            for (int u = 0; u < 8; ++u) {
                int e = u * 256 + tl;
                int kk = e >> 6, col = e & 63;
                Bs[kk * 68 + col] = m2[(a0 + kk) * 512 + c0 + col];
            }
            __syncthreads();
#pragma unroll 8
            for (int kk = 0; kk < 32; ++kk) {
                float av0 = As[kk * 33 + 2 * ty], av1 = As[kk * 33 + 2 * ty + 1];
                float4 bv = *(float4*)&Bs[kk * 68 + 4 * tx];
                a00 += av0 * bv.x; a01 += av0 * bv.y; a02 += av0 * bv.z; a03 += av0 * bv.w;
                a10 += av1 * bv.x; a11 += av1 * bv.y; a12 += av1 * bv.z; a13 += av1 * bv.w;
            }
        }
        int b_ = b0 + 2 * ty;
        float rowv[2][4] = {{a00, a01, a02, a03}, {a10, a11, a12, a13}};
#pragma unroll
        for (int jj = 0; jj < 4; ++jj) {
            int col = c0 + 4 * tx + jj;
            int I = col >> 7, p = col & 127;
            Tn[I * 16384 + p * 128 + b_] = rowv[0][jj];
            Tn[I * 16384 + p * 128 + b_ + 1] = rowv[1][jj];
        }
    }
}

// ---------------- phase B (512 threads, grid 144) ---------------------------
// 4x4 microtile, 4-way k-split (z = t>>7, 128 thr, 4 chunks each), As stored
// transposed stride-36 (4-row-aligned b128), 4-way LDS reduce. Energy blocks
// 0..127 (prefetched); norm blocks 128..143 (same structure, 16 chunks).
__global__ __launch_bounds__(512) void k_B2(float* __restrict__ ws, int k) {
    __shared__ __align__(16) float sm[13312];
    int bid = blockIdx.x, t = threadIdx.x;
    int z = t >> 7, tl = t & 127;        // 4 z-groups x 128 threads
    int ty = tl >> 4, tx = tl & 15;      // 8 x 16 positions; microtile 4x4
    float* As = sm + z * 3328;           // [32k][36] transposed
    float* Bs = sm + z * 3328 + 1152;    // [32k][68]
    float acc[4][4];
#pragma unroll
    for (int j = 0; j < 4; ++j)
#pragma unroll
        for (int q = 0; q < 4; ++q) acc[j][q] = 0.f;
    if (bid < 128) {
        int side = bid >> 6;
        int eb = bid & 63;
        int r0 = (eb & 31) * 32;
        int c0 = (eb >> 5) * 64;
        const float* A = ws + (side ? OFF_T2R : OFF_T2L);
        const float* B = ws + (side ? OFF_MR2 : OFF_M2) + k * M2SZ;
        float* C = ws + (side ? OFF_LR : OFF_LL);
        int arr[2], akq[2], bkk[4], bcq[4];
#pragma unroll
        for (int u = 0; u < 2; ++u) { int e = u * 128 + tl; arr[u] = e >> 3; akq[u] = e & 7; }
#pragma unroll
        for (int u = 0; u < 4; ++u) { int e = u * 128 + tl; bkk[u] = e >> 4; bcq[u] = e & 15; }
        float4 pa[2], pb[4];
        {
            int k0 = (z * 4) * 32;
#pragma unroll
            for (int u = 0; u < 2; ++u)
                pa[u] = *(const float4*)&A[(r0 + arr[u]) * 512 + k0 + akq[u] * 4];
#pragma unroll
            for (int u = 0; u < 4; ++u) {
                int row = k0 + bkk[u];
                pb[u] = *(const float4*)&B[(row >> 2) * 512 + (row & 3) * 128 + c0 + bcq[u] * 4];
            }
        }
        for (int c = 0; c < 4; ++c) {
            __syncthreads();
#pragma unroll
            for (int u = 0; u < 2; ++u) {   // transpose-scatter A into As[kk][36]
                float* dst = &As[(akq[u] * 4) * 36 + arr[u]];
                dst[0] = pa[u].x; dst[36] = pa[u].y; dst[72] = pa[u].z; dst[108] = pa[u].w;
            }
#pragma unroll
            for (int u = 0; u < 4; ++u)
                *(float4*)&Bs[bkk[u] * 68 + bcq[u] * 4] = pb[u];
            if (c < 3) {
                int kn = (z * 4 + c + 1) * 32;
#pragma unroll
                for (int u = 0; u < 2; ++u)
                    pa[u] = *(const float4*)&A[(r0 + arr[u]) * 512 + kn + akq[u] * 4];
#pragma unroll
                for (int u = 0; u < 4; ++u) {
                    int row = kn + bkk[u];
                    pb[u] = *(const float4*)&B[(row >> 2) * 512 + (row & 3) * 128 + c0 + bcq[u] * 4];
                }
            }
            __syncthreads();
#pragma unroll 8
            for (int kk = 0; kk < 32; ++kk) {
                float4 av = *(float4*)&As[kk * 36 + 4 * ty];
                float4 bv = *(float4*)&Bs[kk * 68 + 4 * tx];
                float avv[4] = {av.x, av.y, av.z, av.w};
#pragma unroll
                for (int j = 0; j < 4; ++j) {
                    acc[j][0] += avv[j] * bv.x; acc[j][1] += avv[j] * bv.y;
                    acc[j][2] += avv[j] * bv.z; acc[j][3] += avv[j] * bv.w;
                }
            }
        }
        __syncthreads();
        if (z != 0) {                      // z-buffers dead; reuse as reduce space
#pragma unroll
            for (int j = 0; j < 4; ++j) {
                float4 v; v.x = acc[j][0]; v.y = acc[j][1]; v.z = acc[j][2]; v.w = acc[j][3];
                *(float4*)&sm[z * 3328 + tl * 16 + j * 4] = v;
            }
        }
        __syncthreads();
        if (z == 0) {
#pragma unroll
            for (int zz = 1; zz < 4; ++zz)
#pragma unroll
                for (int j = 0; j < 4; ++j) {
                    float4 v = *(float4*)&sm[zz * 3328 + tl * 16 + j * 4];
                    acc[j][0] += v.x; acc[j][1] += v.y; acc[j][2] += v.z; acc[j][3] += v.w;
                }
#pragma unroll
            for (int j = 0; j < 4; ++j) {
                int r = r0 + 4 * ty + j;
                int cc = c0 + 4 * tx;
                float4 v; v.x = acc[j][0]; v.y = acc[j][1]; v.z = acc[j][2]; v.w = acc[j][3];
                *(float4*)&C[(r >> 3) * 1024 + (r & 7) * 128 + cc] = v;
            }
        }
    } else if (bid < 144) {
        int g = bid - 128;
        int side = g >> 3;
        int nn = g & 7;
        int r0 = (nn & 3) * 32;
        int c0 = (nn >> 2) * 64;
        const float* A = ws + (side ? OFF_TNR : OFF_TNL);    // [I][p][b]
        const float* B = ws + (side ? OFF_MR2 : OFF_M2) + k * M2SZ;
        float* C = ws + (side ? OFF_NR : OFF_NL);
        for (int c = 0; c < 4; ++c) {
            int cg = z * 4 + c;            // 16 chunks = 4z x 4
            int Ic = cg >> 2, bc = (cg & 3) * 32;
            __syncthreads();
#pragma unroll
            for (int u = 0; u < 2; ++u) {
                int e = u * 128 + tl;
                int rr = e >> 3, kq = e & 7;
                const float4 v = *(const float4*)&A[Ic * 16384 + (r0 + rr) * 128 + bc + kq * 4];
                float* dst = &As[(kq * 4) * 36 + rr];
                dst[0] = v.x; dst[36] = v.y; dst[72] = v.z; dst[108] = v.w;
            }
#pragma unroll
            for (int u = 0; u < 4; ++u) {
                int e = u * 128 + tl;
                int kk = e >> 4, cq = e & 15;
                const float4 v = *(const float4*)&B[(bc + kk) * 512 + Ic * 128 + c0 + cq * 4];
                *(float4*)&Bs[kk * 68 + cq * 4] = v;
            }
            __syncthreads();
#pragma unroll 8
            for (int kk = 0; kk < 32; ++kk) {
                float4 av = *(float4*)&As[kk * 36 + 4 * ty];
                float4 bv = *(float4*)&Bs[kk * 68 + 4 * tx];
                float avv[4] = {av.x, av.y, av.z, av.w};
#pragma unroll
                for (int j = 0; j < 4; ++j) {
                    acc[j][0] += avv[j] * bv.x; acc[j][1] += avv[j] * bv.y;
                    acc[j][2] += avv[j] * bv.z; acc[j][3] += avv[j] * bv.w;
                }
            }
        }
        __syncthreads();
        if (z != 0) {
#pragma unroll
            for (int j = 0; j < 4; ++j) {
                float4 v; v.x = acc[j][0]; v.y = acc[j][1]; v.z = acc[j][2]; v.w = acc[j][3];
                *(float4*)&sm[z * 3328 + tl * 16 + j * 4] = v;
            }
        }
        __syncthreads();
        if (z == 0) {
#pragma unroll
            for (int zz = 1; zz < 4; ++zz)
#pragma unroll
                for (int j = 0; j < 4; ++j) {
                    float4 v = *(float4*)&sm[zz * 3328 + tl * 16 + j * 4];
                    acc[j][0] += v.x; acc[j][1] += v.y; acc[j][2] += v.z; acc[j][3] += v.w;
                }
#pragma unroll
            for (int j = 0; j < 4; ++j) {
                int r = r0 + 4 * ty + j;
                int cc = c0 + 4 * tx;
                float4 v; v.x = acc[j][0]; v.y = acc[j][1]; v.z = acc[j][2]; v.w = acc[j][3];
                *(float4*)&C[r * 128 + cc] = v;
            }
        }
    }
}

// ---------------- dot partials + loss (R11 verbatim) ------------------------
__global__ __launch_bounds__(256) void k_dot(float* __restrict__ ws) {
    __shared__ float se[256], sn[256];
    int bid = blockIdx.x, t = threadIdx.x;
    const float* LL = ws + OFF_LL;
    const float* LR = ws + OFF_LR;
    float e = 0.f;
#pragma unroll
    for (int u = 0; u < 4; ++u) {
        int i = bid * 1024 + u * 256 + t;
        e += LL[i] * LR[i];
    }
    float n = 0.f;
    if (t < 128) {
        int i = bid * 128 + t;
        n = ws[OFF_NL + i] * ws[OFF_NR + i];
    }
    se[t] = e;
    sn[t] = n;
    __syncthreads();
    for (int s = 128; s > 0; s >>= 1) {
        if (t < s) { se[t] += se[t + s]; sn[t] += sn[t + s]; }
        __syncthreads();
    }
    if (t == 0) {
        ws[OFF_PART + bid] = se[0];
        ws[OFF_PARTN + bid] = sn[0];
    }
}

__global__ __launch_bounds__(256) void k_loss(const float* __restrict__ ws,
                                              float* __restrict__ out) {
    __shared__ float se[128], sn[128];
    int t = threadIdx.x;
    if (t < 128) {
        se[t] = ws[OFF_PART + t];
        sn[t] = ws[OFF_PARTN + t];
    }
    __syncthreads();
    for (int s = 64; s > 0; s >>= 1) {
        if (t < s) { se[t] += se[t + s]; sn[t] += sn[t + s]; }
        __syncthreads();
    }
    if (t == 0) {
        float E = se[0], Nm = sn[0];
        out[0] = E;
        out[1] = Nm;
        out[2] = E / Nm;
        out[3] = fmaxf(Nm - 10000.0f, 0.0f);
    }
}

extern "C" void kernel_launch(void* const* d_in, const int* in_sizes, int n_in,
                              void* d_out, int out_size, void* d_ws, size_t ws_size,
                              hipStream_t stream) {
    const float* Min = (const float*)d_in[0];
    const float* Hin = (const float*)d_in[1];
    float* ws = (float*)d_ws;
    float* out = (float*)d_out;
    (void)in_sizes; (void)n_in; (void)out_size; (void)ws_size;

    k_prep1<<<dim3(641), dim3(256), 0, stream>>>(Min, Hin, ws);
    k_prep2<<<dim3(640), dim3(256), 0, stream>>>(ws);
    for (int k = 0; k < HALF2; ++k) {
        k_A2<<<dim3(160), dim3(512), 0, stream>>>(ws, k);
        k_B2<<<dim3(144), dim3(512), 0, stream>>>(ws, k);
    }
    k_dot<<<dim3(128), dim3(256), 0, stream>>>(ws);
    k_loss<<<dim3(1), dim3(256), 0, stream>>>(ws, out);
}

// Round 15
// 392.558 us; speedup vs baseline: 1.0636x; 1.0636x over previous
//
#include <hip/hip_runtime.h>

// VariationalMPS R17: 1024-THREAD phases (4 waves/SIMD, was 2) to hide the
// ~7us/phase stall term via TLP — the only lever consistent with all data
// (R9->R11: +waves = -30%; R13-R16 issue-side attacks: null/regressed).
//  eA: z (t>>8) splits a 4-way, single chunk each (stage-sync-compute-sync-
//      reduce; 3 barriers), R14 inner loop verbatim, LDS 139KB.
//  eB: z splits k 4-way (4 chunks each), R11's proven 2-barrier+prefetch
//      chunk loop verbatim, 4-way LDS reduce, LDS 77KB.
//  Norm paths: same bodies, z = task (A) / k-quarter (B), 16 blocks each.
// preps, dot, loss verbatim.

#define D 128
#define W 8
#define NS 40
#define NPAIR 20
#define HALF2 10
#define MSZ (D * 2 * D)        // 32768
#define HSZ (W * W * 2 * 2)    // 256
#define M2SZ (D * 4 * D)       // 65536  [a][I][c] = a*512+I*128+c
#define H2SZ (W * W * 4 * 4)   // 1024   [w][x][I][J]
#define LSZ (D * W * D)        // 131072 [a][w][b] (= [p][x][q] after B)
#define NSZ (D * D)            // 16384
#define T2SZ (D * W * D * 4)   // 524288 row(p,x)*512 + b*4+J
#define TNSZ (4 * D * D)       // 65536  [I][p][b]

#define OFF_M2 0
#define OFF_MR2 (OFF_M2 + NPAIR * M2SZ)
#define OFF_H2 (OFF_MR2 + HALF2 * M2SZ)
#define OFF_HR2 (OFF_H2 + NPAIR * H2SZ)
#define OFF_LL (OFF_HR2 + HALF2 * H2SZ)
#define OFF_LR (OFF_LL + LSZ)
#define OFF_NL (OFF_LR + LSZ)
#define OFF_NR (OFF_NL + NSZ)
#define OFF_T2L (OFF_NR + NSZ)
#define OFF_T2R (OFF_T2L + T2SZ)
#define OFF_TNL (OFF_T2R + T2SZ)
#define OFF_TNR (OFF_TNL + TNSZ)
#define OFF_PART (OFF_TNR + TNSZ)
#define OFF_PARTN (OFF_PART + 128)

// ---------------- prep1: pair GEMMs M2 (640 blocks) + H2 (block 640) --------
__global__ __launch_bounds__(256) void k_prep1(const float* __restrict__ Min,
                                               const float* __restrict__ Hin,
                                               float* __restrict__ ws) {
    __shared__ float As[32 * 34];
    __shared__ float Bs[32 * 68];
    int bid = blockIdx.x, t = threadIdx.x;
    if (bid < 640) {
        int m = bid >> 5, tile = bid & 31;
        int r0 = (tile & 7) * 32, c0 = (tile >> 3) * 64;
        const float* A = Min + (2 * m) * MSZ;
        const float* B = Min + (2 * m + 1) * MSZ;
        float* C = ws + OFF_M2 + m * M2SZ;
        int ty = t >> 4, tx = t & 15;
        float a00 = 0, a01 = 0, a02 = 0, a03 = 0;
        float a10 = 0, a11 = 0, a12 = 0, a13 = 0;
        for (int c = 0; c < 4; ++c) {
            int k0 = c * 32;
            __syncthreads();
            {
                int rr = t >> 3, kq = t & 7;
                int row = r0 + rr;
                const float4 v = *(const float4*)&A[(row >> 1) * 256 + (row & 1) * 128 + k0 + kq * 4];
                float* dst = &As[kq * 136 + rr];
                dst[0] = v.x; dst[34] = v.y; dst[68] = v.z; dst[102] = v.w;
            }
#pragma unroll
            for (int u = 0; u < 2; ++u) {
                int e = u * 256 + t;
                int kk = e >> 4, cq = e & 15;
                const float4 v = *(const float4*)&B[(k0 + kk) * 256 + c0 + cq * 4];
                *(float4*)&Bs[kk * 68 + cq * 4] = v;
            }
            __syncthreads();
#pragma unroll 8
            for (int kk = 0; kk < 32; ++kk) {
                float2 av = *(float2*)&As[kk * 34 + 2 * ty];
                float4 bv = *(float4*)&Bs[kk * 68 + 4 * tx];
                a00 += av.x * bv.x; a01 += av.x * bv.y; a02 += av.x * bv.z; a03 += av.x * bv.w;
                a10 += av.y * bv.x; a11 += av.y * bv.y; a12 += av.y * bv.z; a13 += av.y * bv.w;
            }
        }
        int r = r0 + 2 * ty, cc = c0 + 4 * tx;
        int a = r >> 1, i2 = cc >> 7, cd = cc & 127;
        float4 v0; v0.x = a00; v0.y = a01; v0.z = a02; v0.w = a03;
        float4 v1; v1.x = a10; v1.y = a11; v1.z = a12; v1.w = a13;
        *(float4*)&C[a * 512 + (0 * 2 + i2) * 128 + cd] = v0;
        *(float4*)&C[a * 512 + (1 * 2 + i2) * 128 + cd] = v1;
    } else {
        for (int idx = t; idx < NPAIR * H2SZ; idx += 256) {
            int m = idx >> 10, r = idx & 1023;
            int w = r >> 7, x = (r >> 4) & 7, I = (r >> 2) & 3, J = r & 3;
            int i1 = I >> 1, i2 = I & 1, j1 = J >> 1, j2 = J & 1;
            const float* Ha = Hin + (2 * m) * HSZ;
            const float* Hb = Hin + (2 * m + 1) * HSZ;
            float s = 0.f;
#pragma unroll
            for (int v = 0; v < 8; ++v)
                s += Ha[w * 32 + v * 4 + i1 * 2 + j1] * Hb[v * 32 + x * 4 + i2 * 2 + j2];
            ws[OFF_H2 + idx] = s;
        }
    }
}

// ---------------- prep2: rev transposes + env init --------------------------
#define PR_MR (HALF2 * M2SZ)
#define PR_HR (PR_MR + HALF2 * H2SZ)
#define PR_TOT (PR_HR + 2 * LSZ + 2 * NSZ)
__global__ __launch_bounds__(256) void k_prep2(float* __restrict__ ws) {
    for (int idx = blockIdx.x * 256 + threadIdx.x; idx < PR_TOT; idx += gridDim.x * 256) {
        if (idx < PR_MR) {
            int kr = idx >> 16, r = idx & 65535;
            int a = r >> 9, I = (r >> 7) & 3, p = r & 127;
            ws[OFF_MR2 + idx] = ws[OFF_M2 + (19 - kr) * M2SZ + p * 512 + I * 128 + a];
        } else if (idx < PR_HR) {
            int e = idx - PR_MR;
            int kr = e >> 10, r = e & 1023;
            int w = r >> 7, x = (r >> 4) & 7, lo = r & 15;
            ws[OFF_HR2 + e] = ws[OFF_H2 + (19 - kr) * H2SZ + x * 128 + w * 16 + lo];
        } else {
            int e = idx - PR_HR;
            int off; float v = 0.f;
            if (e < LSZ)            { off = OFF_LL + e; if (e == 0) v = 1.f; }
            else if (e < 2 * LSZ)   { int r = e - LSZ; off = OFF_LR + r; if (r == (W - 1) * D) v = 1.f; }
            else if (e < 2 * LSZ + NSZ) { int r = e - 2 * LSZ; off = OFF_NL + r; if (r == 0) v = 1.f; }
            else                    { int r = e - 2 * LSZ - NSZ; off = OFF_NR + r; if (r == 0) v = 1.f; }
            ws[off] = v;
        }
    }
}

// ---------------- phase A (1024 threads, grid 144) --------------------------
// Energy blocks 0..127: z = t>>8 splits a 4-way (one 32-a chunk each):
// stage -> sync -> compute (R14 inner loop) -> sync -> 4-way LDS reduce ->
// z0 h2-fuse + store. Norm blocks 128..143: z = independent task (64 tasks).
__global__ __launch_bounds__(1024) void k_A2(float* __restrict__ ws, int k) {
    __shared__ __align__(16) float sm[34816];
    int bid = blockIdx.x, t = threadIdx.x;
    int z = t >> 8, tl = t & 255;
    if (bid < 128) {
        int side = bid >> 6;
        int eb = bid & 63;
        int b0 = (eb & 7) * 16;
        int p0 = (eb >> 3) * 16;
        const float* Lsrc = ws + (side ? OFF_LR : OFF_LL);
        const float* m2 = ws + (side ? OFF_MR2 : OFF_M2) + k * M2SZ;
        const float* h2 = ws + (side ? OFF_HR2 : OFF_H2) + k * H2SZ;
        float* T2 = ws + (side ? OFF_T2R : OFF_T2L);
        float* Ls = sm + z * 6400;          // [32a][16b][12w-pad] stride 200
        float* ms = sm + 25600 + z * 2048;  // [32a][16p][4I]
        float* hs = sm + 33792;             // [32 wI][32 xJ]
        {   // stage h2: 1024 elems, 1 per thread
            int e = t;
            int w = e >> 7, I = (e >> 5) & 3, x = (e >> 2) & 7, J = e & 3;
            hs[e] = h2[w * 128 + x * 16 + I * 4 + J];
        }
        int b_l = tl & 15, p_l = tl >> 4;
        float acc[8][4];
#pragma unroll
        for (int w = 0; w < 8; ++w)
#pragma unroll
            for (int I = 0; I < 4; ++I) acc[w][I] = 0.f;
        int a0 = z * 32;    // this z's single chunk
        {   // stage: 4x float4 of L + 2x float4 of M2 per thread (R14 coords)
#pragma unroll
            for (int u = 0; u < 4; ++u) {
                int e = u * 256 + tl;
                int la = e >> 5, lw = (e >> 2) & 7, lb = e & 3;
                const float4 v = *(const float4*)&Lsrc[(a0 + la) * 1024 + lw * 128 + b0 + lb * 4];
                float* dst = &Ls[la * 200 + lb * 48 + lw];
                dst[0] = v.x; dst[12] = v.y; dst[24] = v.z; dst[36] = v.w;
            }
#pragma unroll
            for (int u = 0; u < 2; ++u) {
                int e = u * 256 + tl;
                int maa = e >> 4, mI = (e >> 2) & 3, mpq = e & 3;
                const float4 v = *(const float4*)&m2[(a0 + maa) * 512 + mI * 128 + p0 + mpq * 4];
                int base = maa * 64 + mpq * 16 + mI;   // ms[aa][p][I]
                ms[base] = v.x; ms[base + 4] = v.y;
                ms[base + 8] = v.z; ms[base + 12] = v.w;
            }
        }
        __syncthreads();
#pragma unroll 4
        for (int aa = 0; aa < 32; ++aa) {
            float4 l0 = *(float4*)&Ls[aa * 200 + b_l * 12];
            float4 l1 = *(float4*)&Ls[aa * 200 + b_l * 12 + 4];
            float4 mv = *(float4*)&ms[aa * 64 + p_l * 4];
            float lv[8] = {l0.x, l0.y, l0.z, l0.w, l1.x, l1.y, l1.z, l1.w};
#pragma unroll
            for (int w = 0; w < 8; ++w) {
                acc[w][0] += lv[w] * mv.x;
                acc[w][1] += lv[w] * mv.y;
                acc[w][2] += lv[w] * mv.z;
                acc[w][3] += lv[w] * mv.w;
            }
        }
        __syncthreads();          // all Ls/ms reads done; alias Ls region
        if (z != 0) {
            float* red = sm + (z - 1) * 8192;
#pragma unroll
            for (int w = 0; w < 8; ++w) {
                float4 v; v.x = acc[w][0]; v.y = acc[w][1]; v.z = acc[w][2]; v.w = acc[w][3];
                *(float4*)&red[tl * 32 + w * 4] = v;
            }
        }
        __syncthreads();
        if (z == 0) {
#pragma unroll
            for (int zz = 1; zz < 4; ++zz) {
                float* red = sm + (zz - 1) * 8192;
#pragma unroll
                for (int w = 0; w < 8; ++w) {
                    float4 v = *(float4*)&red[tl * 32 + w * 4];
                    acc[w][0] += v.x; acc[w][1] += v.y; acc[w][2] += v.z; acc[w][3] += v.w;
                }
            }
            float o[32];
#pragma unroll
            for (int xJ = 0; xJ < 32; ++xJ) o[xJ] = 0.f;
#pragma unroll
            for (int wI = 0; wI < 32; ++wI) {
                float tv = acc[wI >> 2][wI & 3];
#pragma unroll
                for (int xJ = 0; xJ < 32; ++xJ) o[xJ] += tv * hs[wI * 32 + xJ];
            }
            int b = b0 + b_l, p = p0 + p_l;
#pragma unroll
            for (int x = 0; x < 8; ++x) {
                float4 v; v.x = o[x * 4]; v.y = o[x * 4 + 1];
                v.z = o[x * 4 + 2]; v.w = o[x * 4 + 3];
                *(float4*)&T2[p * 4096 + x * 512 + b * 4] = v;
            }
        }
    } else {
        int g = (bid - 128) * 4 + z;     // 64 norm tasks over 16 blocks
        int side = g >> 5;
        int nn = g & 31;
        int b0 = (nn & 3) * 32;
        int c0 = (nn >> 2) * 64;
        const float* Nsrc = ws + (side ? OFF_NR : OFF_NL);
        const float* m2 = ws + (side ? OFF_MR2 : OFF_M2) + k * M2SZ;
        float* Tn = ws + (side ? OFF_TNR : OFF_TNL);
        float* As = sm + z * 3264;        // [32][33]
        float* Bs = sm + z * 3264 + 1056; // [32][68]
        int ty = tl >> 4, tx = tl & 15;
        float a00 = 0, a01 = 0, a02 = 0, a03 = 0;
        float a10 = 0, a11 = 0, a12 = 0, a13 = 0;
        for (int c = 0; c < 4; ++c) {
            int a0 = c * 32;
            __syncthreads();
#pragma unroll
            for (int u = 0; u < 4; ++u) {
                int e = u * 256 + tl;
                int kk = e >> 5, col = e & 31;
                As[kk * 33 + col] = Nsrc[(a0 + kk) * 128 + b0 + col];
            }
#pragma unroll
            for (int u = 0; u < 8; ++u) {
                int e = u * 256 + tl;
                int kk = e >> 6, col = e & 63;
                Bs[kk * 68 + col] = m2[(a0 + kk) * 512 + c0 + col];
            }
            __syncthreads();
#pragma unroll 8
            for (int kk = 0; kk < 32; ++kk) {
                float av0 = As[kk * 33 + 2 * ty], av1 = As[kk * 33 + 2 * ty + 1];
                float4 bv = *(float4*)&Bs[kk * 68 + 4 * tx];
                a00 += av0 * bv.x; a01 += av0 * bv.y; a02 += av0 * bv.z; a03 += av0 * bv.w;
                a10 += av1 * bv.x; a11 += av1 * bv.y; a12 += av1 * bv.z; a13 += av1 * bv.w;
            }
        }
        int b_ = b0 + 2 * ty;
        float rowv[2][4] = {{a00, a01, a02, a03}, {a10, a11, a12, a13}};
#pragma unroll
        for (int jj = 0; jj < 4; ++jj) {
            int col = c0 + 4 * tx + jj;
            int I = col >> 7, p = col & 127;
            Tn[I * 16384 + p * 128 + b_] = rowv[0][jj];
            Tn[I * 16384 + p * 128 + b_ + 1] = rowv[1][jj];
        }
    }
}

// ---------------- phase B (1024 threads, grid 144) --------------------------
// Energy blocks 0..127: z = t>>8 splits k 4-way (4 chunks of 32 each); R11's
// 2-barrier + 1-ahead-prefetch chunk loop; 4-way LDS reduce; z0 stores.
// Norm blocks 128..143: same structure over Tn (16 chunks = 4z x 4).
__global__ __launch_bounds__(1024) void k_B2(float* __restrict__ ws, int k) {
    __shared__ __align__(16) float sm[19200];
    int bid = blockIdx.x, t = threadIdx.x;
    int z = t >> 8, tl = t & 255;
    int ty = tl >> 4, tx = tl & 15;
    float a00 = 0, a01 = 0, a02 = 0, a03 = 0;
    float a10 = 0, a11 = 0, a12 = 0, a13 = 0;
    float* As = sm + z * 3264;        // [32][34] = 1088
    float* Bs = sm + z * 3264 + 1088; // [32][68] = 2176
    float* red = sm + 13056;          // 3 x 2048
    if (bid < 128) {
        int side = bid >> 6;
        int eb = bid & 63;
        int r0 = (eb & 31) * 32;
        int c0 = (eb >> 5) * 64;
        const float* A = ws + (side ? OFF_T2R : OFF_T2L);
        const float* B = ws + (side ? OFF_MR2 : OFF_M2) + k * M2SZ;
        float* C = ws + (side ? OFF_LR : OFF_LL);
        int rr = tl >> 3, kq = tl & 7;
        int kkb0 = tl >> 4, cq0 = tl & 15;
        int kkb1 = (256 + tl) >> 4, cq1 = tl & 15;
        int k0 = (z * 4) * 32;
        float4 pa = *(const float4*)&A[(r0 + rr) * 512 + k0 + kq * 4];
        int row0 = k0 + kkb0, row1 = k0 + kkb1;
        float4 pb0 = *(const float4*)&B[(row0 >> 2) * 512 + (row0 & 3) * 128 + c0 + cq0 * 4];
        float4 pb1 = *(const float4*)&B[(row1 >> 2) * 512 + (row1 & 3) * 128 + c0 + cq1 * 4];
        for (int c = 0; c < 4; ++c) {
            __syncthreads();
            {
                float* dst = &As[kq * 136 + rr];
                dst[0] = pa.x; dst[34] = pa.y; dst[68] = pa.z; dst[102] = pa.w;
                *(float4*)&Bs[kkb0 * 68 + cq0 * 4] = pb0;
                *(float4*)&Bs[kkb1 * 68 + cq1 * 4] = pb1;
            }
            if (c < 3) {
                int kn = (z * 4 + c + 1) * 32;
                pa = *(const float4*)&A[(r0 + rr) * 512 + kn + kq * 4];
                int r0n = kn + kkb0, r1n = kn + kkb1;
                pb0 = *(const float4*)&B[(r0n >> 2) * 512 + (r0n & 3) * 128 + c0 + cq0 * 4];
                pb1 = *(const float4*)&B[(r1n >> 2) * 512 + (r1n & 3) * 128 + c0 + cq1 * 4];
            }
            __syncthreads();
#pragma unroll 8
            for (int kk = 0; kk < 32; ++kk) {
                float av0 = As[kk * 34 + 2 * ty], av1 = As[kk * 34 + 2 * ty + 1];
                float4 bv = *(float4*)&Bs[kk * 68 + 4 * tx];
                a00 += av0 * bv.x; a01 += av0 * bv.y; a02 += av0 * bv.z; a03 += av0 * bv.w;
                a10 += av1 * bv.x; a11 += av1 * bv.y; a12 += av1 * bv.z; a13 += av1 * bv.w;
            }
        }
        __syncthreads();
        if (z != 0) {
            float* rz = red + (z - 1) * 2048;
            float4 v0; v0.x = a00; v0.y = a01; v0.z = a02; v0.w = a03;
            float4 v1; v1.x = a10; v1.y = a11; v1.z = a12; v1.w = a13;
            *(float4*)&rz[tl * 8] = v0;
            *(float4*)&rz[tl * 8 + 4] = v1;
        }
        __syncthreads();
        if (z == 0) {
#pragma unroll
            for (int zz = 1; zz < 4; ++zz) {
                float* rz = red + (zz - 1) * 2048;
                float4 v0 = *(float4*)&rz[tl * 8];
                float4 v1 = *(float4*)&rz[tl * 8 + 4];
                a00 += v0.x; a01 += v0.y; a02 += v0.z; a03 += v0.w;
                a10 += v1.x; a11 += v1.y; a12 += v1.z; a13 += v1.w;
            }
            int r = r0 + 2 * ty, cc = c0 + 4 * tx;
            float4 w0; w0.x = a00; w0.y = a01; w0.z = a02; w0.w = a03;
            float4 w1; w1.x = a10; w1.y = a11; w1.z = a12; w1.w = a13;
            *(float4*)&C[(r >> 3) * 1024 + (r & 7) * 128 + cc] = w0;
            *(float4*)&C[((r + 1) >> 3) * 1024 + ((r + 1) & 7) * 128 + cc] = w1;
        }
    } else if (bid < 144) {
        int g = bid - 128;
        int side = g >> 3;
        int nn = g & 7;
        int r0 = (nn & 3) * 32;
        int c0 = (nn >> 2) * 64;
        const float* A = ws + (side ? OFF_TNR : OFF_TNL);   // [I][p][b]
        const float* B = ws + (side ? OFF_MR2 : OFF_M2) + k * M2SZ;
        float* C = ws + (side ? OFF_NR : OFF_NL);
        for (int c = 0; c < 4; ++c) {
            int cg = z * 4 + c;            // 16 chunks = 4z x 4
            int Ic = cg >> 2, bc = (cg & 3) * 32;
            __syncthreads();
            {
                int rr = tl >> 3, kq = tl & 7;
                const float4 v = *(const float4*)&A[Ic * 16384 + (r0 + rr) * 128 + bc + kq * 4];
                float* dst = &As[kq * 136 + rr];
                dst[0] = v.x; dst[34] = v.y; dst[68] = v.z; dst[102] = v.w;
            }
#pragma unroll
            for (int u = 0; u < 2; ++u) {
                int e = u * 256 + tl;
                int kk = e >> 4, cq = e & 15;
                const float4 v = *(const float4*)&B[(bc + kk) * 512 + Ic * 128 + c0 + cq * 4];
                *(float4*)&Bs[kk * 68 + cq * 4] = v;
            }
            __syncthreads();
#pragma unroll 8
            for (int kk = 0; kk < 32; ++kk) {
                float av0 = As[kk * 34 + 2 * ty], av1 = As[kk * 34 + 2 * ty + 1];
                float4 bv = *(float4*)&Bs[kk * 68 + 4 * tx];
                a00 += av0 * bv.x; a01 += av0 * bv.y; a02 += av0 * bv.z; a03 += av0 * bv.w;
                a10 += av1 * bv.x; a11 += av1 * bv.y; a12 += av1 * bv.z; a13 += av1 * bv.w;
            }
        }
        __syncthreads();
        if (z != 0) {
            float* rz = red + (z - 1) * 2048;
            float4 v0; v0.x = a00; v0.y = a01; v0.z = a02; v0.w = a03;
            float4 v1; v1.x = a10; v1.y = a11; v1.z = a12; v1.w = a13;
            *(float4*)&rz[tl * 8] = v0;
            *(float4*)&rz[tl * 8 + 4] = v1;
        }
        __syncthreads();
        if (z == 0) {
#pragma unroll
            for (int zz = 1; zz < 4; ++zz) {
                float* rz = red + (zz - 1) * 2048;
                float4 v0 = *(float4*)&rz[tl * 8];
                float4 v1 = *(float4*)&rz[tl * 8 + 4];
                a00 += v0.x; a01 += v0.y; a02 += v0.z; a03 += v0.w;
                a10 += v1.x; a11 += v1.y; a12 += v1.z; a13 += v1.w;
            }
            int r = r0 + 2 * ty, cc = c0 + 4 * tx;
            float4 w0; w0.x = a00; w0.y = a01; w0.z = a02; w0.w = a03;
            float4 w1; w1.x = a10; w1.y = a11; w1.z = a12; w1.w = a13;
            *(float4*)&C[r * 128 + cc] = w0;
            *(float4*)&C[(r + 1) * 128 + cc] = w1;
        }
    }
}

// ---------------- dot partials + loss (verbatim) ----------------------------
__global__ __launch_bounds__(256) void k_dot(float* __restrict__ ws) {
    __shared__ float se[256], sn[256];
    int bid = blockIdx.x, t = threadIdx.x;
    const float* LL = ws + OFF_LL;
    const float* LR = ws + OFF_LR;
    float e = 0.f;
#pragma unroll
    for (int u = 0; u < 4; ++u) {
        int i = bid * 1024 + u * 256 + t;
        e += LL[i] * LR[i];
    }
    float n = 0.f;
    if (t < 128) {
        int i = bid * 128 + t;
        n = ws[OFF_NL + i] * ws[OFF_NR + i];
    }
    se[t] = e;
    sn[t] = n;
    __syncthreads();
    for (int s = 128; s > 0; s >>= 1) {
        if (t < s) { se[t] += se[t + s]; sn[t] += sn[t + s]; }
        __syncthreads();
    }
    if (t == 0) {
        ws[OFF_PART + bid] = se[0];
        ws[OFF_PARTN + bid] = sn[0];
    }
}

__global__ __launch_bounds__(256) void k_loss(const float* __restrict__ ws,
                                              float* __restrict__ out) {
    __shared__ float se[128], sn[128];
    int t = threadIdx.x;
    if (t < 128) {
        se[t] = ws[OFF_PART + t];
        sn[t] = ws[OFF_PARTN + t];
    }
    __syncthreads();
    for (int s = 64; s > 0; s >>= 1) {
        if (t < s) { se[t] += se[t + s]; sn[t] += sn[t + s]; }
        __syncthreads();
    }
    if (t == 0) {
        float E = se[0], Nm = sn[0];
        out[0] = E;
        out[1] = Nm;
        out[2] = E / Nm;
        out[3] = fmaxf(Nm - 10000.0f, 0.0f);
    }
}

extern "C" void kernel_launch(void* const* d_in, const int* in_sizes, int n_in,
                              void* d_out, int out_size, void* d_ws, size_t ws_size,
                              hipStream_t stream) {
    const float* Min = (const float*)d_in[0];
    const float* Hin = (const float*)d_in[1];
    float* ws = (float*)d_ws;
    float* out = (float*)d_out;
    (void)in_sizes; (void)n_in; (void)out_size; (void)ws_size;

    k_prep1<<<dim3(641), dim3(256), 0, stream>>>(Min, Hin, ws);
    k_prep2<<<dim3(640), dim3(256), 0, stream>>>(ws);
    for (int k = 0; k < HALF2; ++k) {
        k_A2<<<dim3(144), dim3(1024), 0, stream>>>(ws, k);
        k_B2<<<dim3(144), dim3(1024), 0, stream>>>(ws, k);
    }
    k_dot<<<dim3(128), dim3(256), 0, stream>>>(ws);
    k_loss<<<dim3(1), dim3(256), 0, stream>>>(ws, out);
}